// Round 3
// baseline (4752.822 us; speedup 1.0000x reference)
//
#include <hip/hip_runtime.h>

#define D 128
#define N_ITER 40

struct EntR3 { int c; float w; };

// flags[0]: edges are 32-bit (some odd word nonzero)
// flags[1]: mask odd word nonzero   flags[2]: mask word > 1
// flags[3]: mask halfword non-float-like   flags[4]: mask low-halfword float-like
// flags[5]: x (and output) are bf16
__device__ __forceinline__ int r3_mask_mode(const int* f) {
    if (!f[2]) return f[1] ? 1 : 2;   // words all 0/1: int32 vs int64
    if (!f[3]) return f[4] ? 3 : 1;   // float-like: 16-bit vs fp32 words
    return 0;                          // byte bool
}
__device__ __forceinline__ bool r3_get_mask(const void* m, int i, int mode) {
    if (mode == 2) return ((const unsigned int*)m)[2 * (long long)i] != 0u;
    if (mode == 1) return ((const unsigned int*)m)[i] != 0u;
    if (mode == 3) return ((const unsigned short*)m)[i] != 0u;
    return ((const unsigned char*)m)[i] != 0u;
}
__device__ __forceinline__ int r3_erow(const int* e32, int e, int i, int is64) {
    return is64 ? e32[2 * (long long)i] : e32[i];
}
__device__ __forceinline__ int r3_ecol(const int* e32, int e, int i, int is64) {
    return is64 ? e32[2 * ((long long)e + i)] : e32[(long long)e + i];
}
__device__ __forceinline__ unsigned short r3_f2bf(float f) {
    unsigned int u = __float_as_uint(f);
    unsigned int r = 0x7fffu + ((u >> 16) & 1u);
    return (unsigned short)((u + r) >> 16);
}
__device__ __forceinline__ int r3_bf16ish(unsigned int h) {
    if (h == 0u) return 1;
    unsigned int ex = (h >> 7) & 0xFFu;
    return (ex >= 100u && ex <= 140u) ? 1 : 0;
}

__global__ void r3_zero(int* p, long long cnt) {
    long long t = (long long)blockIdx.x * blockDim.x + threadIdx.x;
    long long st = (long long)gridDim.x * blockDim.x;
    for (; t < cnt; t += st) p[t] = 0;
}

__global__ void r3_detect(const int* edges, int e, const unsigned int* mask, int n,
                          const unsigned int* x, int* flags) {
    __shared__ int sh_votes;
    if (threadIdx.x == 0) sh_votes = 0;
    __syncthreads();
    int t = threadIdx.x;
    int f_e32 = 0, f_odd = 0, f_01 = 0, f_hw = 0, f_h0 = 0;
    for (int i = t; i < 65536; i += 256) {
        long long j = ((long long)i * e) >> 16;        // j in [0,e)
        if (edges[2 * j + 1] != 0) f_e32 = 1;          // in-bounds for both layouts
    }
    int mw = n >> 2;                                    // byte layout has n/4 words
    for (int i = t; i < mw; i += 256) {
        unsigned int w = mask[i];
        if ((i & 1) && w) f_odd = 1;
        if (w > 1u) f_01 = 1;
        unsigned int h0 = w & 0xFFFFu, h1 = w >> 16;
        if ((h0 && h0 != 0x3F80u && h0 != 0x3C00u) ||
            (h1 && h1 != 0x3F80u && h1 != 0x3C00u)) f_hw = 1;
        if (h0 == 0x3F80u || h0 == 0x3C00u) f_h0 = 1;
    }
    long long xw = (long long)n * (D / 2);              // minimal (bf16) word count of x
    int my = 0;
    for (int s = t; s < 4096; s += 256) {
        long long j = ((long long)s * xw) >> 12;
        unsigned int w = x[j];
        if (r3_bf16ish(w & 0xFFFFu) && r3_bf16ish(w >> 16)) my++;
    }
    atomicAdd(&sh_votes, my);
    if (f_e32) atomicOr(&flags[0], 1);
    if (f_odd) atomicOr(&flags[1], 1);
    if (f_01)  atomicOr(&flags[2], 1);
    if (f_hw)  atomicOr(&flags[3], 1);
    if (f_h0)  atomicOr(&flags[4], 1);
    __syncthreads();
    if (threadIdx.x == 0) flags[5] = (sh_votes * 2 >= 4096) ? 1 : 0;
}

__global__ void r3_deg(const int* edges, int e, int* deg, const int* flags) {
    int i = blockIdx.x * blockDim.x + threadIdx.x;
    if (i >= e) return;
    int is64 = (flags[0] == 0);
    atomicAdd(&deg[r3_erow(edges, e, i, is64)], 1);
}

__global__ void r3_dinv_start(const int* deg, float* dinv, int* start, int* total, int n) {
    int i = blockIdx.x * blockDim.x + threadIdx.x;
    if (i >= n) return;
    int d = deg[i];
    dinv[i] = (d > 0) ? (1.0f / sqrtf((float)d)) : 0.0f;
    start[i] = atomicAdd(total, d);
}

__global__ void r3_fill(const int* edges, int e, const float* dinv, const int* start,
                        int* cursor, EntR3* ents, const int* flags) {
    int i = blockIdx.x * blockDim.x + threadIdx.x;
    if (i >= e) return;
    int is64 = (flags[0] == 0);
    int r = r3_erow(edges, e, i, is64);
    int c = r3_ecol(edges, e, i, is64);
    int p = start[r] + atomicAdd(&cursor[r], 1);
    EntR3 en; en.c = c; en.w = dinv[r] * dinv[c];
    ents[p] = en;
}

// ---------- Path A: fp32 state ----------
__global__ void r3_init_a(const void* x, const void* mask, float* A, float* B,
                          int n, const int* flags) {
    int t = blockIdx.x * blockDim.x + threadIdx.x;
    if (t >= n * (D / 4)) return;
    int node = t >> 5;
    int mm = r3_mask_mode(flags);
    int xbf = flags[5];
    float4 v = make_float4(0.f, 0.f, 0.f, 0.f);
    if (r3_get_mask(mask, node, mm)) {
        if (xbf) {
            uint2 u = ((const uint2*)x)[t];
            v.x = __uint_as_float(u.x << 16);
            v.y = __uint_as_float(u.x & 0xFFFF0000u);
            v.z = __uint_as_float(u.y << 16);
            v.w = __uint_as_float(u.y & 0xFFFF0000u);
        } else {
            v = ((const float4*)x)[t];
        }
    }
    ((float4*)A)[t] = v;
    ((float4*)B)[t] = v;
}

__global__ void r3_prop_a(const float* src, float* dst, const EntR3* ents,
                          const int* start, const int* degv, const void* mask,
                          const int* flags, int n) {
    int w = (blockIdx.x * blockDim.x + threadIdx.x) >> 6;
    int lane = threadIdx.x & 63;
    if (w >= n) return;
    int mm = r3_mask_mode(flags);
    if (r3_get_mask(mask, w, mm)) return;
    int s = start[w], dg = degv[w];
    const EntR3* ep = ents + s;
    float ax = 0.f, ay = 0.f;
    for (int i = 0; i < dg; ++i) {
        EntR3 en = ep[i];
        float2 v = ((const float2*)(src + (long long)en.c * D))[lane];
        ax = fmaf(en.w, v.x, ax);
        ay = fmaf(en.w, v.y, ay);
    }
    float2 o; o.x = ax; o.y = ay;
    ((float2*)(dst + (long long)w * D))[lane] = o;
}

__global__ void r3_final_a(const float* src, void* out, int n, const int* flags) {
    int t = blockIdx.x * blockDim.x + threadIdx.x;
    if (t >= n * (D / 4)) return;
    float4 v = ((const float4*)src)[t];
    if (flags[5]) {
        uint2 o;
        o.x = (unsigned int)r3_f2bf(v.x) | ((unsigned int)r3_f2bf(v.y) << 16);
        o.y = (unsigned int)r3_f2bf(v.z) | ((unsigned int)r3_f2bf(v.w) << 16);
        ((uint2*)out)[t] = o;
    } else {
        ((float4*)out)[t] = v;
    }
}

// ---------- Path B: bf16 state (low-ws fallback) ----------
__global__ void r3_init_b(const void* x, const void* mask, unsigned int* A, unsigned int* B,
                          int n, const int* flags) {
    int t = blockIdx.x * blockDim.x + threadIdx.x;
    if (t >= n * (D / 2)) return;                   // one u32 = 2 elements
    int node = t >> 6;
    int mm = r3_mask_mode(flags);
    int xbf = flags[5];
    unsigned int w = 0u;
    if (r3_get_mask(mask, node, mm)) {
        if (xbf) {
            w = ((const unsigned int*)x)[t];
        } else {
            float2 f = ((const float2*)x)[t];
            w = (unsigned int)r3_f2bf(f.x) | ((unsigned int)r3_f2bf(f.y) << 16);
        }
    }
    A[t] = w;
    B[t] = w;
}

__global__ void r3_prop_b(const unsigned int* src, unsigned int* dst, const EntR3* ents,
                          const int* start, const int* degv, const void* mask,
                          const int* flags, int n) {
    int w = (blockIdx.x * blockDim.x + threadIdx.x) >> 6;
    int lane = threadIdx.x & 63;
    if (w >= n) return;
    int mm = r3_mask_mode(flags);
    if (r3_get_mask(mask, w, mm)) return;
    int s = start[w], dg = degv[w];
    const EntR3* ep = ents + s;
    float ax = 0.f, ay = 0.f;
    for (int i = 0; i < dg; ++i) {
        EntR3 en = ep[i];
        unsigned int v = src[(long long)en.c * (D / 2) + lane];
        ax = fmaf(en.w, __uint_as_float(v << 16), ax);
        ay = fmaf(en.w, __uint_as_float(v & 0xFFFF0000u), ay);
    }
    dst[(long long)w * (D / 2) + lane] =
        (unsigned int)r3_f2bf(ax) | ((unsigned int)r3_f2bf(ay) << 16);
}

__global__ void r3_final_b(const unsigned int* src, void* out, int n, const int* flags) {
    int t = blockIdx.x * blockDim.x + threadIdx.x;
    if (t >= n * (D / 2)) return;
    unsigned int w = src[t];
    if (flags[5]) {
        ((unsigned int*)out)[t] = w;
    } else {
        float2 f;
        f.x = __uint_as_float(w << 16);
        f.y = __uint_as_float(w & 0xFFFF0000u);
        ((float2*)out)[t] = f;
    }
}

extern "C" void kernel_launch(void* const* d_in, const int* in_sizes, int n_in,
                              void* d_out, int out_size, void* d_ws, size_t ws_size,
                              hipStream_t stream) {
    const void* x    = d_in[0];
    const int* edges = (const int*)d_in[1];
    const void* mask = d_in[2];
    int n = in_sizes[0] / D;
    int e = in_sizes[1] / 2;

    char* ws = (char*)d_ws;
    size_t off = 0;
    int* flags  = (int*)(ws + off); off += 64 * sizeof(int);
    int* deg    = (int*)(ws + off); off += (size_t)n * sizeof(int);
    int* cursor = (int*)(ws + off); off += (size_t)n * sizeof(int);
    int* total  = (int*)(ws + off); off += 64 * sizeof(int);
    long long zcount = 2LL * n + 128;              // flags..total contiguous ints
    int*   start = (int*)(ws + off);   off += (size_t)n * sizeof(int);
    float* dinv  = (float*)(ws + off); off += (size_t)n * sizeof(float);
    off = (off + 255) & ~(size_t)255;
    EntR3* ents = (EntR3*)(ws + off);  off += (size_t)e * sizeof(EntR3);
    off = (off + 255) & ~(size_t)255;

    size_t fbytes = (size_t)n * D * sizeof(float);
    size_t hbytes = (size_t)n * D * 2;
    int useA = (ws_size >= off + 2 * fbytes) ? 1 : 0;

    r3_zero<<<512, 256, 0, stream>>>(flags, zcount);
    r3_detect<<<1, 256, 0, stream>>>(edges, e, (const unsigned int*)mask, n,
                                     (const unsigned int*)x, flags);
    r3_deg<<<(e + 255) / 256, 256, 0, stream>>>(edges, e, deg, flags);
    r3_dinv_start<<<(n + 255) / 256, 256, 0, stream>>>(deg, dinv, start, total, n);
    r3_fill<<<(e + 255) / 256, 256, 0, stream>>>(edges, e, dinv, start, cursor, ents, flags);

    if (useA) {
        float* A = (float*)(ws + off);
        float* B = (float*)(ws + off + fbytes);
        int q = n * (D / 4);
        r3_init_a<<<(q + 255) / 256, 256, 0, stream>>>(x, mask, A, B, n, flags);
        float* src = A; float* dst = B;
        for (int it = 0; it < N_ITER; ++it) {
            r3_prop_a<<<(n + 3) / 4, 256, 0, stream>>>(src, dst, ents, start, deg, mask, flags, n);
            float* tmp = src; src = dst; dst = tmp;
        }
        r3_final_a<<<(q + 255) / 256, 256, 0, stream>>>(src, d_out, n, flags);
    } else {
        unsigned int* A = (unsigned int*)(ws + off);
        unsigned int* B = (unsigned int*)(ws + off + hbytes);
        int q = n * (D / 2);
        r3_init_b<<<(q + 255) / 256, 256, 0, stream>>>(x, mask, A, B, n, flags);
        unsigned int* src = A; unsigned int* dst = B;
        for (int it = 0; it < N_ITER; ++it) {
            r3_prop_b<<<(n + 3) / 4, 256, 0, stream>>>(src, dst, ents, start, deg, mask, flags, n);
            unsigned int* tmp = src; src = dst; dst = tmp;
        }
        r3_final_b<<<(q + 255) / 256, 256, 0, stream>>>(src, d_out, n, flags);
    }
}

// Round 4
// 1920.634 us; speedup vs baseline: 2.4746x; 2.4746x over previous
//
#include <hip/hip_runtime.h>

#define D 128
#define N_ITER 40

struct Ent4 { int c; float w; };

// flags[0]: edges are 32-bit   flags[1]: mask odd word nonzero
// flags[2]: mask word > 1      flags[3]: mask halfword non-float-like
// flags[4]: mask low-halfword float-like
// flags[6]: x-is-bf16 votes (of 4096)   flags[7]: unmasked row count
// flags[8]: running total for CSR start offsets
__device__ __forceinline__ int r4_mask_mode(const int* f) {
    if (!f[2]) return f[1] ? 1 : 2;   // words all 0/1: int32 vs int64
    if (!f[3]) return f[4] ? 3 : 1;   // float-like: 16-bit vs fp32 words
    return 0;                          // byte bool
}
__device__ __forceinline__ bool r4_get_mask(const void* m, int i, int mode) {
    if (mode == 2) return ((const unsigned int*)m)[2 * (long long)i] != 0u;
    if (mode == 1) return ((const unsigned int*)m)[i] != 0u;
    if (mode == 3) return ((const unsigned short*)m)[i] != 0u;
    return ((const unsigned char*)m)[i] != 0u;
}
__device__ __forceinline__ int r4_xbf(const int* f) { return (f[6] * 2 >= 4096) ? 1 : 0; }
__device__ __forceinline__ int r4_erow(const int* e32, int e, int i, int is64) {
    return is64 ? e32[2 * (long long)i] : e32[i];
}
__device__ __forceinline__ int r4_ecol(const int* e32, int e, int i, int is64) {
    return is64 ? e32[2 * ((long long)e + i)] : e32[(long long)e + i];
}
__device__ __forceinline__ unsigned short r4_f2bf(float f) {
    unsigned int u = __float_as_uint(f);
    unsigned int r = 0x7fffu + ((u >> 16) & 1u);
    return (unsigned short)((u + r) >> 16);
}
__device__ __forceinline__ int r4_bf16ish(unsigned int h) {
    if (h == 0u) return 1;
    unsigned int ex = (h >> 7) & 0xFFu;
    return (ex >= 100u && ex <= 140u) ? 1 : 0;
}
__device__ __forceinline__ float r4_lo(unsigned int v) { return __uint_as_float(v << 16); }
__device__ __forceinline__ float r4_hi(unsigned int v) { return __uint_as_float(v & 0xFFFF0000u); }

__global__ void r4_zero(int* p, long long cnt) {
    long long t = (long long)blockIdx.x * blockDim.x + threadIdx.x;
    long long st = (long long)gridDim.x * blockDim.x;
    for (; t < cnt; t += st) p[t] = 0;
}

__global__ void r4_detect(const int* __restrict__ edges, int e,
                          const unsigned int* __restrict__ mask, int n,
                          const unsigned int* __restrict__ x, int* __restrict__ flags) {
    __shared__ int sh_votes;
    if (threadIdx.x == 0) sh_votes = 0;
    __syncthreads();
    int t = blockIdx.x * blockDim.x + threadIdx.x;
    int stride = gridDim.x * blockDim.x;
    int f_e32 = 0, f_odd = 0, f_01 = 0, f_hw = 0, f_h0 = 0;
    for (int i = t; i < 65536; i += stride) {
        long long j = ((long long)i * e) >> 16;        // j in [0,e)
        if (edges[2 * j + 1] != 0) f_e32 = 1;          // in-bounds for both layouts
    }
    int mw = n >> 2;                                    // byte layout has n/4 words
    for (int i = t; i < mw; i += stride) {
        unsigned int w = mask[i];
        if ((i & 1) && w) f_odd = 1;
        if (w > 1u) f_01 = 1;
        unsigned int h0 = w & 0xFFFFu, h1 = w >> 16;
        if ((h0 && h0 != 0x3F80u && h0 != 0x3C00u) ||
            (h1 && h1 != 0x3F80u && h1 != 0x3C00u)) f_hw = 1;
        if (h0 == 0x3F80u || h0 == 0x3C00u) f_h0 = 1;
    }
    long long xw = (long long)n * (D / 2);              // minimal (bf16) word count of x
    int my = 0;
    for (int s = t; s < 4096; s += stride) {
        long long j = ((long long)s * xw) >> 12;
        unsigned int w = x[j];
        if (r4_bf16ish(w & 0xFFFFu) && r4_bf16ish(w >> 16)) my++;
    }
    if (my) atomicAdd(&sh_votes, my);
    if (f_e32) atomicOr(&flags[0], 1);
    if (f_odd) atomicOr(&flags[1], 1);
    if (f_01)  atomicOr(&flags[2], 1);
    if (f_hw)  atomicOr(&flags[3], 1);
    if (f_h0)  atomicOr(&flags[4], 1);
    __syncthreads();
    if (threadIdx.x == 0 && sh_votes) atomicAdd(&flags[6], sh_votes);
}

__global__ void r4_deg(const int* __restrict__ edges, int e, int* __restrict__ deg,
                       const int* __restrict__ flags) {
    int i = blockIdx.x * blockDim.x + threadIdx.x;
    if (i >= e) return;
    int is64 = (flags[0] == 0);
    atomicAdd(&deg[r4_erow(edges, e, i, is64)], 1);
}

// dinv + start offsets + compacted unmasked-row list
__global__ void r4_dinv_start(const int* __restrict__ deg, float* __restrict__ dinv,
                              int* __restrict__ start, int* __restrict__ rowlist,
                              const void* __restrict__ mask, int* __restrict__ flags, int n) {
    int i = blockIdx.x * blockDim.x + threadIdx.x;
    if (i >= n) return;
    int d = deg[i];
    dinv[i] = (d > 0) ? (1.0f / sqrtf((float)d)) : 0.0f;
    start[i] = atomicAdd(&flags[8], d);
    int mm = r4_mask_mode(flags);
    if (!r4_get_mask(mask, i, mm)) {
        rowlist[atomicAdd(&flags[7], 1)] = i;
    }
}

__global__ void r4_fill(const int* __restrict__ edges, int e, const float* __restrict__ dinv,
                        const int* __restrict__ start, int* __restrict__ cursor,
                        Ent4* __restrict__ ents, const int* __restrict__ flags) {
    int i = blockIdx.x * blockDim.x + threadIdx.x;
    if (i >= e) return;
    int is64 = (flags[0] == 0);
    int r = r4_erow(edges, e, i, is64);
    int c = r4_ecol(edges, e, i, is64);
    int p = start[r] + atomicAdd(&cursor[r], 1);
    Ent4 en; en.c = c; en.w = dinv[r] * dinv[c];
    ents[p] = en;
}

// init bf16 state in A and B (masked rows = x, unmasked = 0); masked rows also to d_out
__global__ void r4_init(const void* __restrict__ x, const void* __restrict__ mask,
                        unsigned int* __restrict__ A, unsigned int* __restrict__ B,
                        void* __restrict__ out, int n, const int* __restrict__ flags) {
    int t = blockIdx.x * blockDim.x + threadIdx.x;
    if (t >= n * (D / 2)) return;                  // one u32 = 2 bf16 elems
    int node = t >> 6;
    int mm = r4_mask_mode(flags);
    int xbf = r4_xbf(flags);
    bool m = r4_get_mask(mask, node, mm);
    unsigned int w = 0u;
    float2 f = make_float2(0.f, 0.f);
    if (m) {
        if (xbf) {
            w = ((const unsigned int*)x)[t];
        } else {
            f = ((const float2*)x)[t];
            w = (unsigned int)r4_f2bf(f.x) | ((unsigned int)r4_f2bf(f.y) << 16);
        }
    }
    A[t] = w;
    B[t] = w;
    if (m) {
        if (xbf) ((unsigned int*)out)[t] = w;
        else     ((float2*)out)[t] = f;
    }
}

__device__ __forceinline__ void r4_accum(const unsigned int* __restrict__ src,
                                         const Ent4* __restrict__ ep, int dg, int lane,
                                         float& ax, float& ay) {
    int i = 0;
    for (; i + 4 <= dg; i += 4) {
        Ent4 e0 = ep[i], e1 = ep[i + 1], e2 = ep[i + 2], e3 = ep[i + 3];
        unsigned int v0 = src[(long long)e0.c * (D / 2) + lane];
        unsigned int v1 = src[(long long)e1.c * (D / 2) + lane];
        unsigned int v2 = src[(long long)e2.c * (D / 2) + lane];
        unsigned int v3 = src[(long long)e3.c * (D / 2) + lane];
        ax = fmaf(e0.w, r4_lo(v0), ax); ay = fmaf(e0.w, r4_hi(v0), ay);
        ax = fmaf(e1.w, r4_lo(v1), ax); ay = fmaf(e1.w, r4_hi(v1), ay);
        ax = fmaf(e2.w, r4_lo(v2), ax); ay = fmaf(e2.w, r4_hi(v2), ay);
        ax = fmaf(e3.w, r4_lo(v3), ax); ay = fmaf(e3.w, r4_hi(v3), ay);
    }
    for (; i < dg; ++i) {
        Ent4 en = ep[i];
        unsigned int v = src[(long long)en.c * (D / 2) + lane];
        ax = fmaf(en.w, r4_lo(v), ax); ay = fmaf(en.w, r4_hi(v), ay);
    }
}

__global__ __launch_bounds__(256) void r4_prop(
        const unsigned int* __restrict__ src, unsigned int* __restrict__ dst,
        const Ent4* __restrict__ ents, const int* __restrict__ start,
        const int* __restrict__ degv, const int* __restrict__ rowlist,
        const int* __restrict__ flags) {
    int wi = (blockIdx.x * blockDim.x + threadIdx.x) >> 6;
    int lane = threadIdx.x & 63;
    if (wi >= flags[7]) return;
    int row = rowlist[wi];
    float ax = 0.f, ay = 0.f;
    r4_accum(src, ents + start[row], degv[row], lane, ax, ay);
    dst[(long long)row * (D / 2) + lane] =
        (unsigned int)r4_f2bf(ax) | ((unsigned int)r4_f2bf(ay) << 16);
}

__global__ __launch_bounds__(256) void r4_prop_final(
        const unsigned int* __restrict__ src, void* __restrict__ out,
        const Ent4* __restrict__ ents, const int* __restrict__ start,
        const int* __restrict__ degv, const int* __restrict__ rowlist,
        const int* __restrict__ flags) {
    int wi = (blockIdx.x * blockDim.x + threadIdx.x) >> 6;
    int lane = threadIdx.x & 63;
    if (wi >= flags[7]) return;
    int row = rowlist[wi];
    float ax = 0.f, ay = 0.f;
    r4_accum(src, ents + start[row], degv[row], lane, ax, ay);
    long long idx = (long long)row * (D / 2) + lane;
    if (r4_xbf(flags)) {
        ((unsigned int*)out)[idx] =
            (unsigned int)r4_f2bf(ax) | ((unsigned int)r4_f2bf(ay) << 16);
    } else {
        float2 f; f.x = ax; f.y = ay;
        ((float2*)out)[idx] = f;
    }
}

extern "C" void kernel_launch(void* const* d_in, const int* in_sizes, int n_in,
                              void* d_out, int out_size, void* d_ws, size_t ws_size,
                              hipStream_t stream) {
    const void* x    = d_in[0];
    const int* edges = (const int*)d_in[1];
    const void* mask = d_in[2];
    int n = in_sizes[0] / D;
    int e = in_sizes[1] / 2;

    char* ws = (char*)d_ws;
    size_t off = 0;
    int* flags   = (int*)(ws + off); off += 64 * sizeof(int);
    int* deg     = (int*)(ws + off); off += (size_t)n * sizeof(int);
    int* cursor  = (int*)(ws + off); off += (size_t)n * sizeof(int);
    long long zcount = 2LL * n + 64;                 // flags..cursor contiguous ints
    int* start   = (int*)(ws + off);   off += (size_t)n * sizeof(int);
    float* dinv  = (float*)(ws + off); off += (size_t)n * sizeof(float);
    int* rowlist = (int*)(ws + off);   off += (size_t)n * sizeof(int);
    off = (off + 255) & ~(size_t)255;
    Ent4* ents = (Ent4*)(ws + off);    off += (size_t)e * sizeof(Ent4);
    off = (off + 255) & ~(size_t)255;
    size_t hbytes = (size_t)n * D * 2;               // bf16 state buffer
    unsigned int* A = (unsigned int*)(ws + off);
    unsigned int* B = (unsigned int*)(ws + off + hbytes);

    r4_zero<<<256, 256, 0, stream>>>(flags, zcount);
    r4_detect<<<128, 256, 0, stream>>>(edges, e, (const unsigned int*)mask, n,
                                       (const unsigned int*)x, flags);
    r4_deg<<<(e + 255) / 256, 256, 0, stream>>>(edges, e, deg, flags);
    r4_dinv_start<<<(n + 255) / 256, 256, 0, stream>>>(deg, dinv, start, rowlist, mask, flags, n);
    r4_fill<<<(e + 255) / 256, 256, 0, stream>>>(edges, e, dinv, start, cursor, ents, flags);

    int q = n * (D / 2);
    r4_init<<<(q + 255) / 256, 256, 0, stream>>>(x, mask, A, B, d_out, n, flags);

    unsigned int* src = A;
    unsigned int* dst = B;
    int pb = (n + 3) / 4;                            // waves cover all n; extras exit on flags[7]
    for (int it = 0; it < N_ITER - 1; ++it) {
        r4_prop<<<pb, 256, 0, stream>>>(src, dst, ents, start, deg, rowlist, flags);
        unsigned int* tmp = src; src = dst; dst = tmp;
    }
    r4_prop_final<<<pb, 256, 0, stream>>>(src, d_out, ents, start, deg, rowlist, flags);
}

// Round 5
// 1692.180 us; speedup vs baseline: 2.8087x; 1.1350x over previous
//
#include <hip/hip_runtime.h>

#define D 128
#define N_ITER 40

struct Ent5 { int c; float w; };

// flags[0]: edges 32-bit  [1]: mask odd word nz  [2]: mask word>1
// [3]: mask halfword non-float-like  [4]: mask low-halfword float-like
// [6]: x-is-bf16 votes (of 4096)  [7]: unmasked row count
// [9]: total masked-col entries    [10]: total unmasked-col entries
__device__ __forceinline__ int r5_mask_mode(const int* f) {
    if (!f[2]) return f[1] ? 1 : 2;
    if (!f[3]) return f[4] ? 3 : 1;
    return 0;
}
__device__ __forceinline__ bool r5_get_mask(const void* m, int i, int mode) {
    if (mode == 2) return ((const unsigned int*)m)[2 * (long long)i] != 0u;
    if (mode == 1) return ((const unsigned int*)m)[i] != 0u;
    if (mode == 3) return ((const unsigned short*)m)[i] != 0u;
    return ((const unsigned char*)m)[i] != 0u;
}
__device__ __forceinline__ int r5_xbf(const int* f) { return (f[6] * 2 >= 4096) ? 1 : 0; }
__device__ __forceinline__ int r5_erow(const int* e32, int e, int i, int is64) {
    return is64 ? e32[2 * (long long)i] : e32[i];
}
__device__ __forceinline__ int r5_ecol(const int* e32, int e, int i, int is64) {
    return is64 ? e32[2 * ((long long)e + i)] : e32[(long long)e + i];
}
__device__ __forceinline__ unsigned short r5_f2bf(float f) {
    unsigned int u = __float_as_uint(f);
    unsigned int r = 0x7fffu + ((u >> 16) & 1u);
    return (unsigned short)((u + r) >> 16);
}
__device__ __forceinline__ int r5_bf16ish(unsigned int h) {
    if (h == 0u) return 1;
    unsigned int ex = (h >> 7) & 0xFFu;
    return (ex >= 100u && ex <= 140u) ? 1 : 0;
}
__device__ __forceinline__ float r5_lo(unsigned int v) { return __uint_as_float(v << 16); }
__device__ __forceinline__ float r5_hi(unsigned int v) { return __uint_as_float(v & 0xFFFF0000u); }
__device__ __forceinline__ unsigned int r5_pack(float a, float b) {
    return (unsigned int)r5_f2bf(a) | ((unsigned int)r5_f2bf(b) << 16);
}

__global__ void r5_zero(int* p, long long cnt) {
    long long t = (long long)blockIdx.x * blockDim.x + threadIdx.x;
    long long st = (long long)gridDim.x * blockDim.x;
    for (; t < cnt; t += st) p[t] = 0;
}

__global__ void r5_detect(const int* __restrict__ edges, int e,
                          const unsigned int* __restrict__ mask, int n,
                          const unsigned int* __restrict__ x, int* __restrict__ flags) {
    __shared__ int sh_votes;
    if (threadIdx.x == 0) sh_votes = 0;
    __syncthreads();
    int t = blockIdx.x * blockDim.x + threadIdx.x;
    int stride = gridDim.x * blockDim.x;
    int f_e32 = 0, f_odd = 0, f_01 = 0, f_hw = 0, f_h0 = 0;
    for (int i = t; i < 65536; i += stride) {
        long long j = ((long long)i * e) >> 16;
        if (edges[2 * j + 1] != 0) f_e32 = 1;
    }
    int mw = n >> 2;
    for (int i = t; i < mw; i += stride) {
        unsigned int w = mask[i];
        if ((i & 1) && w) f_odd = 1;
        if (w > 1u) f_01 = 1;
        unsigned int h0 = w & 0xFFFFu, h1 = w >> 16;
        if ((h0 && h0 != 0x3F80u && h0 != 0x3C00u) ||
            (h1 && h1 != 0x3F80u && h1 != 0x3C00u)) f_hw = 1;
        if (h0 == 0x3F80u || h0 == 0x3C00u) f_h0 = 1;
    }
    long long xw = (long long)n * (D / 2);
    int my = 0;
    for (int s = t; s < 4096; s += stride) {
        long long j = ((long long)s * xw) >> 12;
        unsigned int w = x[j];
        if (r5_bf16ish(w & 0xFFFFu) && r5_bf16ish(w >> 16)) my++;
    }
    if (my) atomicAdd(&sh_votes, my);
    if (f_e32) atomicOr(&flags[0], 1);
    if (f_odd) atomicOr(&flags[1], 1);
    if (f_01)  atomicOr(&flags[2], 1);
    if (f_hw)  atomicOr(&flags[3], 1);
    if (f_h0)  atomicOr(&flags[4], 1);
    __syncthreads();
    if (threadIdx.x == 0 && sh_votes) atomicAdd(&flags[6], sh_votes);
}

__global__ void r5_deg(const int* __restrict__ edges, int e, int* __restrict__ deg,
                       const int* __restrict__ flags) {
    int i = blockIdx.x * blockDim.x + threadIdx.x;
    if (i >= e) return;
    int is64 = (flags[0] == 0);
    atomicAdd(&deg[r5_erow(edges, e, i, is64)], 1);
}

__global__ void r5_rows(const int* __restrict__ deg, float* __restrict__ dinv,
                        int* __restrict__ rowlist, const void* __restrict__ mask,
                        int* __restrict__ flags, int n) {
    int i = blockIdx.x * blockDim.x + threadIdx.x;
    if (i >= n) return;
    int d = deg[i];
    dinv[i] = (d > 0) ? (1.0f / sqrtf((float)d)) : 0.0f;
    int mm = r5_mask_mode(flags);
    if (!r5_get_mask(mask, i, mm)) rowlist[atomicAdd(&flags[7], 1)] = i;
}

// count masked-col / unmasked-col entries per unmasked row (into start_m/start_u)
__global__ void r5_deg2(const int* __restrict__ edges, int e, const void* __restrict__ mask,
                        int* __restrict__ start_m, int* __restrict__ start_u,
                        const int* __restrict__ flags) {
    int i = blockIdx.x * blockDim.x + threadIdx.x;
    if (i >= e) return;
    int is64 = (flags[0] == 0);
    int mm = r5_mask_mode(flags);
    int r = r5_erow(edges, e, i, is64);
    if (r5_get_mask(mask, r, mm)) return;
    int c = r5_ecol(edges, e, i, is64);
    if (r5_get_mask(mask, c, mm)) atomicAdd(&start_m[r], 1);
    else                          atomicAdd(&start_u[r], 1);
}

__global__ void r5_offsets(int* __restrict__ start_m, int* __restrict__ start_u,
                           int* __restrict__ flags, int n) {
    int i = blockIdx.x * blockDim.x + threadIdx.x;
    if (i >= n) return;
    int cm = start_m[i];
    int cu = start_u[i];
    start_m[i] = atomicAdd(&flags[9], cm);
    start_u[i] = atomicAdd(&flags[10], cu);
}

__global__ void r5_fill(const int* __restrict__ edges, int e, const float* __restrict__ dinv,
                        const int* __restrict__ start_m, const int* __restrict__ start_u,
                        int* __restrict__ cur_m, int* __restrict__ cur_u,
                        Ent5* __restrict__ ents_m, Ent5* __restrict__ ents_u,
                        const void* __restrict__ mask, const int* __restrict__ flags) {
    int i = blockIdx.x * blockDim.x + threadIdx.x;
    if (i >= e) return;
    int is64 = (flags[0] == 0);
    int mm = r5_mask_mode(flags);
    int r = r5_erow(edges, e, i, is64);
    if (r5_get_mask(mask, r, mm)) return;
    int c = r5_ecol(edges, e, i, is64);
    Ent5 en; en.c = c; en.w = dinv[r] * dinv[c];
    if (r5_get_mask(mask, c, mm)) ents_m[start_m[r] + atomicAdd(&cur_m[r], 1)] = en;
    else                          ents_u[start_u[r] + atomicAdd(&cur_u[r], 1)] = en;
}

// unrolled gather-accumulate from packed-bf16 src
__device__ __forceinline__ void r5_accum(const unsigned int* __restrict__ src,
                                         const Ent5* __restrict__ ep, int dg, int lane,
                                         float& ax, float& ay) {
    int i = 0;
    for (; i + 8 <= dg; i += 8) {
        Ent5 e0 = ep[i], e1 = ep[i+1], e2 = ep[i+2], e3 = ep[i+3];
        Ent5 e4 = ep[i+4], e5 = ep[i+5], e6 = ep[i+6], e7 = ep[i+7];
        unsigned int v0 = src[(long long)e0.c * (D/2) + lane];
        unsigned int v1 = src[(long long)e1.c * (D/2) + lane];
        unsigned int v2 = src[(long long)e2.c * (D/2) + lane];
        unsigned int v3 = src[(long long)e3.c * (D/2) + lane];
        unsigned int v4 = src[(long long)e4.c * (D/2) + lane];
        unsigned int v5 = src[(long long)e5.c * (D/2) + lane];
        unsigned int v6 = src[(long long)e6.c * (D/2) + lane];
        unsigned int v7 = src[(long long)e7.c * (D/2) + lane];
        ax = fmaf(e0.w, r5_lo(v0), ax); ay = fmaf(e0.w, r5_hi(v0), ay);
        ax = fmaf(e1.w, r5_lo(v1), ax); ay = fmaf(e1.w, r5_hi(v1), ay);
        ax = fmaf(e2.w, r5_lo(v2), ax); ay = fmaf(e2.w, r5_hi(v2), ay);
        ax = fmaf(e3.w, r5_lo(v3), ax); ay = fmaf(e3.w, r5_hi(v3), ay);
        ax = fmaf(e4.w, r5_lo(v4), ax); ay = fmaf(e4.w, r5_hi(v4), ay);
        ax = fmaf(e5.w, r5_lo(v5), ax); ay = fmaf(e5.w, r5_hi(v5), ay);
        ax = fmaf(e6.w, r5_lo(v6), ax); ay = fmaf(e6.w, r5_hi(v6), ay);
        ax = fmaf(e7.w, r5_lo(v7), ax); ay = fmaf(e7.w, r5_hi(v7), ay);
    }
    for (; i < dg; ++i) {
        Ent5 en = ep[i];
        unsigned int v = src[(long long)en.c * (D/2) + lane];
        ax = fmaf(en.w, r5_lo(v), ax); ay = fmaf(en.w, r5_hi(v), ay);
    }
}

// one-time: base[row] = sum over masked cols of w * x[col]
__global__ __launch_bounds__(256) void r5_base(
        const void* __restrict__ x, unsigned int* __restrict__ base,
        const Ent5* __restrict__ ents_m, const int* __restrict__ start_m,
        const int* __restrict__ cnt_m, const int* __restrict__ rowlist,
        const int* __restrict__ flags) {
    int wi = (blockIdx.x * blockDim.x + threadIdx.x) >> 6;
    int lane = threadIdx.x & 63;
    if (wi >= flags[7]) return;
    int row = rowlist[wi];
    int s = start_m[row], dg = cnt_m[row];
    float ax = 0.f, ay = 0.f;
    if (r5_xbf(flags)) {
        r5_accum((const unsigned int*)x, ents_m + s, dg, lane, ax, ay);
    } else {
        const float2* xf = (const float2*)x;
        for (int i = 0; i < dg; ++i) {
            Ent5 en = ents_m[s + i];
            float2 v = xf[(long long)en.c * (D/2) + lane];
            ax = fmaf(en.w, v.x, ax); ay = fmaf(en.w, v.y, ay);
        }
    }
    base[(long long)row * (D/2) + lane] = r5_pack(ax, ay);
}

__global__ void r5_init(const void* __restrict__ x, const void* __restrict__ mask,
                        unsigned int* __restrict__ A, unsigned int* __restrict__ B,
                        void* __restrict__ out, int n, const int* __restrict__ flags) {
    int t = blockIdx.x * blockDim.x + threadIdx.x;
    if (t >= n * (D / 2)) return;
    int node = t >> 6;
    int mm = r5_mask_mode(flags);
    int xbf = r5_xbf(flags);
    bool m = r5_get_mask(mask, node, mm);
    unsigned int w = 0u;
    float2 f = make_float2(0.f, 0.f);
    if (m) {
        if (xbf) w = ((const unsigned int*)x)[t];
        else { f = ((const float2*)x)[t]; w = r5_pack(f.x, f.y); }
    }
    A[t] = w;
    B[t] = w;
    if (m) {
        if (xbf) ((unsigned int*)out)[t] = w;
        else     ((float2*)out)[t] = f;
    }
}

__global__ __launch_bounds__(256) void r5_prop(
        const unsigned int* __restrict__ src, unsigned int* __restrict__ dst,
        const unsigned int* __restrict__ base, const Ent5* __restrict__ ents_u,
        const int* __restrict__ start_u, const int* __restrict__ cnt_u,
        const int* __restrict__ rowlist, const int* __restrict__ flags) {
    int wi = (blockIdx.x * blockDim.x + threadIdx.x) >> 6;
    int lane = threadIdx.x & 63;
    if (wi >= flags[7]) return;
    int row = rowlist[wi];
    long long idx = (long long)row * (D/2) + lane;
    unsigned int b = base[idx];
    float ax = r5_lo(b), ay = r5_hi(b);
    r5_accum(src, ents_u + start_u[row], cnt_u[row], lane, ax, ay);
    dst[idx] = r5_pack(ax, ay);
}

__global__ __launch_bounds__(256) void r5_prop_final(
        const unsigned int* __restrict__ src, void* __restrict__ out,
        const unsigned int* __restrict__ base, const Ent5* __restrict__ ents_u,
        const int* __restrict__ start_u, const int* __restrict__ cnt_u,
        const int* __restrict__ rowlist, const int* __restrict__ flags) {
    int wi = (blockIdx.x * blockDim.x + threadIdx.x) >> 6;
    int lane = threadIdx.x & 63;
    if (wi >= flags[7]) return;
    int row = rowlist[wi];
    long long idx = (long long)row * (D/2) + lane;
    unsigned int b = base[idx];
    float ax = r5_lo(b), ay = r5_hi(b);
    r5_accum(src, ents_u + start_u[row], cnt_u[row], lane, ax, ay);
    if (r5_xbf(flags)) {
        ((unsigned int*)out)[idx] = r5_pack(ax, ay);
    } else {
        float2 f; f.x = ax; f.y = ay;
        ((float2*)out)[idx] = f;
    }
}

extern "C" void kernel_launch(void* const* d_in, const int* in_sizes, int n_in,
                              void* d_out, int out_size, void* d_ws, size_t ws_size,
                              hipStream_t stream) {
    const void* x    = d_in[0];
    const int* edges = (const int*)d_in[1];
    const void* mask = d_in[2];
    int n = in_sizes[0] / D;
    int e = in_sizes[1] / 2;

    char* ws = (char*)d_ws;
    size_t off = 0;
    // zero region: flags + deg + cur_m + cur_u + start_m + start_u = 64 + 5n ints
    int* flags   = (int*)(ws + off); off += 64 * sizeof(int);
    int* deg     = (int*)(ws + off); off += (size_t)n * sizeof(int);
    int* cur_m   = (int*)(ws + off); off += (size_t)n * sizeof(int);
    int* cur_u   = (int*)(ws + off); off += (size_t)n * sizeof(int);
    int* start_m = (int*)(ws + off); off += (size_t)n * sizeof(int);
    int* start_u = (int*)(ws + off); off += (size_t)n * sizeof(int);
    long long zcount = 5LL * n + 64;
    float* dinv  = (float*)(ws + off); off += (size_t)n * sizeof(float);
    int* rowlist = (int*)(ws + off);   off += (size_t)n * sizeof(int);
    off = (off + 255) & ~(size_t)255;
    Ent5* ents_m = (Ent5*)(ws + off);  off += (size_t)e * sizeof(Ent5);
    off = (off + 255) & ~(size_t)255;
    Ent5* ents_u = (Ent5*)(ws + off);  off += (size_t)e * sizeof(Ent5);
    off = (off + 255) & ~(size_t)255;
    size_t hbytes = (size_t)n * D * 2;
    unsigned int* base = (unsigned int*)(ws + off); off += hbytes;
    unsigned int* A    = (unsigned int*)(ws + off); off += hbytes;
    unsigned int* B    = (unsigned int*)(ws + off); off += hbytes;

    r5_zero<<<256, 256, 0, stream>>>(flags, zcount);
    r5_detect<<<128, 256, 0, stream>>>(edges, e, (const unsigned int*)mask, n,
                                       (const unsigned int*)x, flags);
    r5_deg<<<(e + 255) / 256, 256, 0, stream>>>(edges, e, deg, flags);
    r5_rows<<<(n + 255) / 256, 256, 0, stream>>>(deg, dinv, rowlist, mask, flags, n);
    r5_deg2<<<(e + 255) / 256, 256, 0, stream>>>(edges, e, mask, start_m, start_u, flags);
    r5_offsets<<<(n + 255) / 256, 256, 0, stream>>>(start_m, start_u, flags, n);
    r5_fill<<<(e + 255) / 256, 256, 0, stream>>>(edges, e, dinv, start_m, start_u,
                                                 cur_m, cur_u, ents_m, ents_u, mask, flags);

    int q = n * (D / 2);
    r5_init<<<(q + 255) / 256, 256, 0, stream>>>(x, mask, A, B, d_out, n, flags);

    int pb = (n + 3) / 4;
    r5_base<<<pb, 256, 0, stream>>>(x, base, ents_m, start_m, cur_m, rowlist, flags);

    unsigned int* src = A;
    unsigned int* dst = B;
    for (int it = 0; it < N_ITER - 1; ++it) {
        r5_prop<<<pb, 256, 0, stream>>>(src, dst, base, ents_u, start_u, cur_u, rowlist, flags);
        unsigned int* tmp = src; src = dst; dst = tmp;
    }
    r5_prop_final<<<pb, 256, 0, stream>>>(src, d_out, base, ents_u, start_u, cur_u,
                                          rowlist, flags);
}

// Round 7
// 1216.089 us; speedup vs baseline: 3.9083x; 1.3915x over previous
//
#include <hip/hip_runtime.h>

#define D 128
#define N_ITER 40
#define DW (D / 2)   // 64 packed-bf16 words per row

struct Ent7 { int c; float w; };

// flags[0]: edges 32-bit  [1]: mask odd word nz  [2]: mask word>1
// [3]: mask halfword non-float-like  [4]: mask low-halfword float-like
// [6]: x-is-bf16 votes (of 4096)  [7]: unmasked row count
// [9]: masked-col entry total      [10]: unmasked-col entry total
__device__ __forceinline__ int r7_mask_mode(const int* f) {
    if (!f[2]) return f[1] ? 1 : 2;
    if (!f[3]) return f[4] ? 3 : 1;
    return 0;
}
__device__ __forceinline__ bool r7_get_mask(const void* m, int i, int mode) {
    if (mode == 2) return ((const unsigned int*)m)[2 * (long long)i] != 0u;
    if (mode == 1) return ((const unsigned int*)m)[i] != 0u;
    if (mode == 3) return ((const unsigned short*)m)[i] != 0u;
    return ((const unsigned char*)m)[i] != 0u;
}
__device__ __forceinline__ int r7_xbf(const int* f) { return (f[6] * 2 >= 4096) ? 1 : 0; }
__device__ __forceinline__ int r7_erow(const int* e32, int e, int i, int is64) {
    return is64 ? e32[2 * (long long)i] : e32[i];
}
__device__ __forceinline__ int r7_ecol(const int* e32, int e, int i, int is64) {
    return is64 ? e32[2 * ((long long)e + i)] : e32[(long long)e + i];
}
__device__ __forceinline__ unsigned short r7_f2bf(float f) {
    unsigned int u = __float_as_uint(f);
    unsigned int r = 0x7fffu + ((u >> 16) & 1u);
    return (unsigned short)((u + r) >> 16);
}
__device__ __forceinline__ int r7_bf16ish(unsigned int h) {
    if (h == 0u) return 1;
    unsigned int ex = (h >> 7) & 0xFFu;
    return (ex >= 100u && ex <= 140u) ? 1 : 0;
}
__device__ __forceinline__ float r7_lo(unsigned int v) { return __uint_as_float(v << 16); }
__device__ __forceinline__ float r7_hi(unsigned int v) { return __uint_as_float(v & 0xFFFF0000u); }
__device__ __forceinline__ unsigned int r7_pack(float a, float b) {
    return (unsigned int)r7_f2bf(a) | ((unsigned int)r7_f2bf(b) << 16);
}
// base lives in d_out's unmasked rows: word index depends on output dtype
__device__ __forceinline__ long long r7_bidx(int row, int lane, int xbf) {
    return xbf ? ((long long)row * DW + lane) : ((long long)row * D + lane);
}

__global__ void r7_zero(int* p, long long cnt) {
    long long t = (long long)blockIdx.x * blockDim.x + threadIdx.x;
    long long st = (long long)gridDim.x * blockDim.x;
    for (; t < cnt; t += st) p[t] = 0;
}

__global__ void r7_detect(const int* __restrict__ edges, int e,
                          const unsigned int* __restrict__ mask, int n,
                          const unsigned int* __restrict__ x, int* __restrict__ flags) {
    __shared__ int sh_votes;
    if (threadIdx.x == 0) sh_votes = 0;
    __syncthreads();
    int t = blockIdx.x * blockDim.x + threadIdx.x;
    int stride = gridDim.x * blockDim.x;
    int f_e32 = 0, f_odd = 0, f_01 = 0, f_hw = 0, f_h0 = 0;
    for (int i = t; i < 65536; i += stride) {
        long long j = ((long long)i * e) >> 16;
        if (edges[2 * j + 1] != 0) f_e32 = 1;
    }
    int mw = n >> 2;
    for (int i = t; i < mw; i += stride) {
        unsigned int w = mask[i];
        if ((i & 1) && w) f_odd = 1;
        if (w > 1u) f_01 = 1;
        unsigned int h0 = w & 0xFFFFu, h1 = w >> 16;
        if ((h0 && h0 != 0x3F80u && h0 != 0x3C00u) ||
            (h1 && h1 != 0x3F80u && h1 != 0x3C00u)) f_hw = 1;
        if (h0 == 0x3F80u || h0 == 0x3C00u) f_h0 = 1;
    }
    long long xw = (long long)n * DW;
    int my = 0;
    for (int s = t; s < 4096; s += stride) {
        long long j = ((long long)s * xw) >> 12;
        unsigned int w = x[j];
        if (r7_bf16ish(w & 0xFFFFu) && r7_bf16ish(w >> 16)) my++;
    }
    if (my) atomicAdd(&sh_votes, my);
    if (f_e32) atomicOr(&flags[0], 1);
    if (f_odd) atomicOr(&flags[1], 1);
    if (f_01)  atomicOr(&flags[2], 1);
    if (f_hw)  atomicOr(&flags[3], 1);
    if (f_h0)  atomicOr(&flags[4], 1);
    __syncthreads();
    if (threadIdx.x == 0 && sh_votes) atomicAdd(&flags[6], sh_votes);
}

__global__ void r7_deg_all(const int* __restrict__ edges, int e,
                           const void* __restrict__ mask, int* __restrict__ deg,
                           int* __restrict__ cnt_m, int* __restrict__ cnt_u,
                           const int* __restrict__ flags) {
    int i = blockIdx.x * blockDim.x + threadIdx.x;
    if (i >= e) return;
    int is64 = (flags[0] == 0);
    int mm = r7_mask_mode(flags);
    int r = r7_erow(edges, e, i, is64);
    atomicAdd(&deg[r], 1);
    if (r7_get_mask(mask, r, mm)) return;
    int c = r7_ecol(edges, e, i, is64);
    if (r7_get_mask(mask, c, mm)) atomicAdd(&cnt_m[r], 1);
    else                          atomicAdd(&cnt_u[r], 1);
}

__global__ void r7_rows(const int* __restrict__ deg, float* __restrict__ dinv,
                        int* __restrict__ rowlist, const void* __restrict__ mask,
                        int* __restrict__ flags, int n) {
    int i = blockIdx.x * blockDim.x + threadIdx.x;
    if (i >= n) return;
    int d = deg[i];
    dinv[i] = (d > 0) ? (1.0f / sqrtf((float)d)) : 0.0f;
    int mm = r7_mask_mode(flags);
    if (!r7_get_mask(mask, i, mm)) rowlist[atomicAdd(&flags[7], 1)] = i;
}

__global__ void r7_offsets(const int* __restrict__ cnt_m, const int* __restrict__ cnt_u,
                           int* __restrict__ start_m, int* __restrict__ start_u,
                           int* __restrict__ flags, int n) {
    int i = blockIdx.x * blockDim.x + threadIdx.x;
    if (i >= n) return;
    start_m[i] = atomicAdd(&flags[9], cnt_m[i]);
    start_u[i] = atomicAdd(&flags[10], cnt_u[i]);
}

__global__ void r7_meta(const int* __restrict__ rowlist, const int* __restrict__ start_u,
                        const int* __restrict__ cnt_u, int4* __restrict__ meta_u,
                        const int* __restrict__ flags) {
    int wi = blockIdx.x * blockDim.x + threadIdx.x;
    if (wi >= flags[7]) return;
    int row = rowlist[wi];
    int4 mu; mu.x = row; mu.y = start_u[row]; mu.z = cnt_u[row]; mu.w = 0;
    meta_u[wi] = mu;
}

__global__ void r7_fill(const int* __restrict__ edges, int e, const float* __restrict__ dinv,
                        const int* __restrict__ start_m, const int* __restrict__ start_u,
                        int* __restrict__ cur_m, int* __restrict__ cur_u,
                        Ent7* __restrict__ ents_m, Ent7* __restrict__ ents_u,
                        const void* __restrict__ mask, const int* __restrict__ flags) {
    int i = blockIdx.x * blockDim.x + threadIdx.x;
    if (i >= e) return;
    int is64 = (flags[0] == 0);
    int mm = r7_mask_mode(flags);
    int r = r7_erow(edges, e, i, is64);
    if (r7_get_mask(mask, r, mm)) return;
    int c = r7_ecol(edges, e, i, is64);
    Ent7 en; en.c = c; en.w = dinv[r] * dinv[c];
    if (r7_get_mask(mask, c, mm)) ents_m[start_m[r] + atomicAdd(&cur_m[r], 1)] = en;
    else                          ents_u[start_u[r] + atomicAdd(&cur_u[r], 1)] = en;
}

// init: masked rows = x into A, B, and d_out; unmasked rows of A/B = 0
__global__ void r7_init(const void* __restrict__ x, const void* __restrict__ mask,
                        unsigned int* __restrict__ A, unsigned int* __restrict__ B,
                        void* __restrict__ out, int n, const int* __restrict__ flags) {
    int t = blockIdx.x * blockDim.x + threadIdx.x;
    if (t >= n * DW) return;
    int node = t >> 6;
    int mm = r7_mask_mode(flags);
    int xbf = r7_xbf(flags);
    bool m = r7_get_mask(mask, node, mm);
    unsigned int w = 0u;
    float2 f = make_float2(0.f, 0.f);
    if (m) {
        if (xbf) w = ((const unsigned int*)x)[t];
        else { f = ((const float2*)x)[t]; w = r7_pack(f.x, f.y); }
    }
    A[t] = w;
    B[t] = w;
    if (m) {
        if (xbf) ((unsigned int*)out)[t] = w;
        else     ((float2*)out)[t] = f;
    }
}

__device__ __forceinline__ void r7_g4(const unsigned int* __restrict__ src,
                                      const Ent7* __restrict__ ep, int i, int lane,
                                      float& ax, float& ay) {
    Ent7 a = ep[i], b = ep[i + 1], c = ep[i + 2], d = ep[i + 3];
    unsigned int va = src[(long long)a.c * DW + lane];
    unsigned int vb = src[(long long)b.c * DW + lane];
    unsigned int vc = src[(long long)c.c * DW + lane];
    unsigned int vd = src[(long long)d.c * DW + lane];
    ax = fmaf(a.w, r7_lo(va), ax); ay = fmaf(a.w, r7_hi(va), ay);
    ax = fmaf(b.w, r7_lo(vb), ax); ay = fmaf(b.w, r7_hi(vb), ay);
    ax = fmaf(c.w, r7_lo(vc), ax); ay = fmaf(c.w, r7_hi(vc), ay);
    ax = fmaf(d.w, r7_lo(vd), ax); ay = fmaf(d.w, r7_hi(vd), ay);
}
__device__ __forceinline__ void r7_g1(const unsigned int* __restrict__ src,
                                      const Ent7* __restrict__ ep, int i, int lane,
                                      float& ax, float& ay) {
    Ent7 a = ep[i];
    unsigned int va = src[(long long)a.c * DW + lane];
    ax = fmaf(a.w, r7_lo(va), ax); ay = fmaf(a.w, r7_hi(va), ay);
}

// one-time base: base[row] = sum over masked cols of w*x[col], stored in d_out's
// unmasked-row slot (dead space until the final iteration overwrites it)
__global__ __launch_bounds__(256) void r7_base(
        const void* __restrict__ x, void* __restrict__ out,
        const Ent7* __restrict__ ents_m, const int* __restrict__ rowlist,
        const int* __restrict__ start_m, const int* __restrict__ cnt_m,
        const int* __restrict__ flags) {
    int wi = (blockIdx.x * blockDim.x + threadIdx.x) >> 6;
    int lane = threadIdx.x & 63;
    if (wi >= flags[7]) return;
    wi = __builtin_amdgcn_readfirstlane(wi);
    int row = __builtin_amdgcn_readfirstlane(rowlist[wi]);
    int s   = __builtin_amdgcn_readfirstlane(start_m[row]);
    int cnt = __builtin_amdgcn_readfirstlane(cnt_m[row]);
    int xbf = r7_xbf(flags);
    float ax = 0.f, ay = 0.f;
    const Ent7* ep = ents_m + s;
    if (xbf) {
        const unsigned int* src = (const unsigned int*)x;
        int i = 0;
        for (; i + 4 <= cnt; i += 4) r7_g4(src, ep, i, lane, ax, ay);
        for (; i < cnt; ++i)         r7_g1(src, ep, i, lane, ax, ay);
    } else {
        const float2* xf = (const float2*)x;
        for (int i = 0; i < cnt; ++i) {
            Ent7 en = ep[i];
            float2 v = xf[(long long)en.c * DW + lane];
            ax = fmaf(en.w, v.x, ax); ay = fmaf(en.w, v.y, ay);
        }
    }
    ((unsigned int*)out)[r7_bidx(row, lane, xbf)] = r7_pack(ax, ay);
}

// propagation: one wave handles TWO rows, interleaved gathers; base read from d_out
__global__ __launch_bounds__(256) void r7_prop(
        const unsigned int* __restrict__ src, unsigned int* __restrict__ dst,
        const void* __restrict__ outbase, const Ent7* __restrict__ ents,
        const int4* __restrict__ meta, const int* __restrict__ flags) {
    int wp = (blockIdx.x * blockDim.x + threadIdx.x) >> 6;
    int lane = threadIdx.x & 63;
    int nr = flags[7];
    int i0 = 2 * wp;
    if (i0 >= nr) return;
    wp = __builtin_amdgcn_readfirstlane(wp);
    i0 = 2 * wp;
    int i1 = i0 + 1;
    bool has1 = (i1 < nr);
    int xbf = r7_xbf(flags);
    int4 m0 = meta[i0];
    int row0 = __builtin_amdgcn_readfirstlane(m0.x);
    int s0   = __builtin_amdgcn_readfirstlane(m0.y);
    int c0   = __builtin_amdgcn_readfirstlane(m0.z);
    int row1 = row0, s1 = 0, c1 = 0;
    if (has1) {
        int4 m1 = meta[i1];
        row1 = __builtin_amdgcn_readfirstlane(m1.x);
        s1   = __builtin_amdgcn_readfirstlane(m1.y);
        c1   = __builtin_amdgcn_readfirstlane(m1.z);
    }
    const unsigned int* bp = (const unsigned int*)outbase;
    unsigned int b0 = bp[r7_bidx(row0, lane, xbf)];
    float a0x = r7_lo(b0), a0y = r7_hi(b0);
    float a1x = 0.f, a1y = 0.f;
    if (has1) {
        unsigned int b1 = bp[r7_bidx(row1, lane, xbf)];
        a1x = r7_lo(b1); a1y = r7_hi(b1);
    }
    const Ent7* e0 = ents + s0;
    const Ent7* e1 = ents + s1;
    int i = 0, j = 0;
    while (i + 4 <= c0 && j + 4 <= c1) {
        r7_g4(src, e0, i, lane, a0x, a0y);
        r7_g4(src, e1, j, lane, a1x, a1y);
        i += 4; j += 4;
    }
    for (; i + 4 <= c0; i += 4) r7_g4(src, e0, i, lane, a0x, a0y);
    for (; i < c0; ++i)         r7_g1(src, e0, i, lane, a0x, a0y);
    for (; j + 4 <= c1; j += 4) r7_g4(src, e1, j, lane, a1x, a1y);
    for (; j < c1; ++j)         r7_g1(src, e1, j, lane, a1x, a1y);
    dst[(long long)row0 * DW + lane] = r7_pack(a0x, a0y);
    if (has1) dst[(long long)row1 * DW + lane] = r7_pack(a1x, a1y);
}

// final: read base from own row of d_out, accumulate, overwrite own row of d_out
__global__ __launch_bounds__(256) void r7_prop_final(
        const unsigned int* __restrict__ src, void* __restrict__ out,
        const Ent7* __restrict__ ents, const int4* __restrict__ meta,
        const int* __restrict__ flags) {
    int wp = (blockIdx.x * blockDim.x + threadIdx.x) >> 6;
    int lane = threadIdx.x & 63;
    int nr = flags[7];
    int i0 = 2 * wp;
    if (i0 >= nr) return;
    wp = __builtin_amdgcn_readfirstlane(wp);
    i0 = 2 * wp;
    int i1 = i0 + 1;
    bool has1 = (i1 < nr);
    int xbf = r7_xbf(flags);
    int4 m0 = meta[i0];
    int row0 = __builtin_amdgcn_readfirstlane(m0.x);
    int s0   = __builtin_amdgcn_readfirstlane(m0.y);
    int c0   = __builtin_amdgcn_readfirstlane(m0.z);
    int row1 = row0, s1 = 0, c1 = 0;
    if (has1) {
        int4 m1 = meta[i1];
        row1 = __builtin_amdgcn_readfirstlane(m1.x);
        s1   = __builtin_amdgcn_readfirstlane(m1.y);
        c1   = __builtin_amdgcn_readfirstlane(m1.z);
    }
    const unsigned int* bp = (const unsigned int*)out;
    unsigned int b0 = bp[r7_bidx(row0, lane, xbf)];
    float a0x = r7_lo(b0), a0y = r7_hi(b0);
    float a1x = 0.f, a1y = 0.f;
    if (has1) {
        unsigned int b1 = bp[r7_bidx(row1, lane, xbf)];
        a1x = r7_lo(b1); a1y = r7_hi(b1);
    }
    const Ent7* e0 = ents + s0;
    const Ent7* e1 = ents + s1;
    int i = 0, j = 0;
    while (i + 4 <= c0 && j + 4 <= c1) {
        r7_g4(src, e0, i, lane, a0x, a0y);
        r7_g4(src, e1, j, lane, a1x, a1y);
        i += 4; j += 4;
    }
    for (; i + 4 <= c0; i += 4) r7_g4(src, e0, i, lane, a0x, a0y);
    for (; i < c0; ++i)         r7_g1(src, e0, i, lane, a0x, a0y);
    for (; j + 4 <= c1; j += 4) r7_g4(src, e1, j, lane, a1x, a1y);
    for (; j < c1; ++j)         r7_g1(src, e1, j, lane, a1x, a1y);
    if (xbf) {
        ((unsigned int*)out)[(long long)row0 * DW + lane] = r7_pack(a0x, a0y);
        if (has1) ((unsigned int*)out)[(long long)row1 * DW + lane] = r7_pack(a1x, a1y);
    } else {
        float2 f0; f0.x = a0x; f0.y = a0y;
        ((float2*)out)[(long long)row0 * DW + lane] = f0;
        if (has1) { float2 f1; f1.x = a1x; f1.y = a1y;
                    ((float2*)out)[(long long)row1 * DW + lane] = f1; }
    }
}

extern "C" void kernel_launch(void* const* d_in, const int* in_sizes, int n_in,
                              void* d_out, int out_size, void* d_ws, size_t ws_size,
                              hipStream_t stream) {
    const void* x    = d_in[0];
    const int* edges = (const int*)d_in[1];
    const void* mask = d_in[2];
    int n = in_sizes[0] / D;
    int e = in_sizes[1] / 2;

    // ---- workspace carve (total ~78 MiB at n=1e5, e=1.6e6; r5's 100.3 MiB fit) ----
    char* ws = (char*)d_ws;
    size_t off = 0;
    int* flags   = (int*)(ws + off); off += 64 * sizeof(int);
    int* deg     = (int*)(ws + off); off += (size_t)n * sizeof(int);
    int* cnt_m   = (int*)(ws + off); off += (size_t)n * sizeof(int);
    int* cnt_u   = (int*)(ws + off); off += (size_t)n * sizeof(int);
    int* cur_m   = (int*)(ws + off); off += (size_t)n * sizeof(int);
    int* cur_u   = (int*)(ws + off); off += (size_t)n * sizeof(int);
    long long zcount = 5LL * n + 64;
    int* start_m = (int*)(ws + off);   off += (size_t)n * sizeof(int);
    int* start_u = (int*)(ws + off);   off += (size_t)n * sizeof(int);
    float* dinv  = (float*)(ws + off); off += (size_t)n * sizeof(float);
    int* rowlist = (int*)(ws + off);   off += (size_t)n * sizeof(int);
    off = (off + 255) & ~(size_t)255;
    int4* meta_u = (int4*)(ws + off);  off += (size_t)n * sizeof(int4);
    Ent7* ents_m = (Ent7*)(ws + off);  off += (size_t)e * sizeof(Ent7);
    off = (off + 255) & ~(size_t)255;
    Ent7* ents_u = (Ent7*)(ws + off);  off += (size_t)e * sizeof(Ent7);
    off = (off + 255) & ~(size_t)255;
    size_t hbytes = (size_t)n * D * 2;
    unsigned int* A = (unsigned int*)(ws + off); off += hbytes;
    unsigned int* B = (unsigned int*)(ws + off); off += hbytes;

    r7_zero<<<256, 256, 0, stream>>>(flags, zcount);
    r7_detect<<<128, 256, 0, stream>>>(edges, e, (const unsigned int*)mask, n,
                                       (const unsigned int*)x, flags);
    r7_deg_all<<<(e + 255) / 256, 256, 0, stream>>>(edges, e, mask, deg, cnt_m, cnt_u, flags);
    r7_rows<<<(n + 255) / 256, 256, 0, stream>>>(deg, dinv, rowlist, mask, flags, n);
    r7_offsets<<<(n + 255) / 256, 256, 0, stream>>>(cnt_m, cnt_u, start_m, start_u, flags, n);
    r7_meta<<<(n + 255) / 256, 256, 0, stream>>>(rowlist, start_u, cnt_u, meta_u, flags);
    r7_fill<<<(e + 255) / 256, 256, 0, stream>>>(edges, e, dinv, start_m, start_u,
                                                 cur_m, cur_u, ents_m, ents_u, mask, flags);

    int q = n * DW;
    r7_init<<<(q + 255) / 256, 256, 0, stream>>>(x, mask, A, B, d_out, n, flags);

    int pb1 = (n + 3) / 4;                        // 1 row/wave upper bound
    r7_base<<<pb1, 256, 0, stream>>>(x, d_out, ents_m, rowlist, start_m, cnt_m, flags);

    int waves2 = (n + 1) / 2;                     // 2 rows/wave upper bound
    int pb2 = (waves2 + 3) / 4;
    unsigned int* src = A;
    unsigned int* dst = B;
    for (int it = 0; it < N_ITER - 1; ++it) {
        r7_prop<<<pb2, 256, 0, stream>>>(src, dst, d_out, ents_u, meta_u, flags);
        unsigned int* tmp = src; src = dst; dst = tmp;
    }
    r7_prop_final<<<pb2, 256, 0, stream>>>(src, d_out, ents_u, meta_u, flags);
}